// Round 1
// baseline (152.196 us; speedup 1.0000x reference)
//
#include <hip/hip_runtime.h>
#include <hip/hip_bf16.h>

// Problem constants (from reference)
#define B 32
#define S 8192
#define D 512
#define CODE_START 256
#define CODE_END 257
#define MEM_TOK 258
#define ADDR_KEY 206
#define MEM_STORE 455

// ---------------------------------------------------------------------------
// Kernel 1: per-row scans.
//  - cs[b][s]  = cummax over s' <= s of (tok==CODE_START ? s' : -1)
//  - fce[b]    = min over s of (tok==CODE_END ? s : S)
// One block (256 threads = 4 waves) per row; 32 chunks of 256 with carry.
// ---------------------------------------------------------------------------
__global__ __launch_bounds__(256) void nvm_scan_kernel(
    const int* __restrict__ tok, int* __restrict__ cs_out, int* __restrict__ fce_out) {
  const int b = blockIdx.x;
  const int tid = threadIdx.x;
  const int lane = tid & 63;
  const int wid = tid >> 6;
  const int* row = tok + b * S;

  // ---- first CODE_END position (min-reduce) ----
  int m = S;
  for (int p = tid; p < S; p += 256) {
    int tk = row[p];
    if (tk == CODE_END && p < m) m = p;
  }
  for (int off = 32; off; off >>= 1) {
    int u = __shfl_down(m, off, 64);
    m = min(m, u);
  }
  __shared__ int red[4];
  if (lane == 0) red[wid] = m;
  __syncthreads();
  if (tid == 0) fce_out[b] = min(min(red[0], red[1]), min(red[2], red[3]));

  // ---- cummax of CODE_START positions ----
  __shared__ int wt[4];
  __shared__ int carry_sh;
  if (tid == 0) carry_sh = -1;
  __syncthreads();

  for (int chunk = 0; chunk < S; chunk += 256) {
    int p = chunk + tid;
    int tk = row[p];
    int v = (tk == CODE_START) ? p : -1;
    // inclusive wave-64 max scan
    #pragma unroll
    for (int off = 1; off < 64; off <<= 1) {
      int u = __shfl_up(v, off, 64);
      if (lane >= off) v = max(v, u);
    }
    if (lane == 63) wt[wid] = v;
    __syncthreads();  // wt visible; carry_sh from prev iter visible
    int pre = carry_sh;
    for (int w = 0; w < wid; ++w) pre = max(pre, wt[w]);
    cs_out[b * S + p] = max(v, pre);
    __syncthreads();  // everyone done reading carry_sh/wt
    if (tid == 0)
      carry_sh = max(max(carry_sh, wt[0]), max(wt[1], max(wt[2], wt[3])));
    __syncthreads();  // carry update visible before next chunk
  }
}

// ---------------------------------------------------------------------------
// Kernel 2: gather + patch + stream out.
// 128 threads per token (each thread one float4 of the 512-dim embedding),
// 2 tokens per 256-thread block. Writes are fully coalesced.
// ---------------------------------------------------------------------------
__global__ __launch_bounds__(256) void nvm_main_kernel(
    const int* __restrict__ tok, const float* __restrict__ table,
    const int* __restrict__ cs_arr, const int* __restrict__ fce_arr,
    const int* __restrict__ mhe_p, float* __restrict__ out) {
  const int t = blockIdx.x * 2 + (threadIdx.x >> 7);  // global token index
  const int lane = threadIdx.x & 127;                 // float4 index within token
  const int b = t >> 13;                              // /S
  const int s = t & (S - 1);

  const int tk = tok[t];
  const int cs = cs_arr[t];
  const int fce = fce_arr[b];
  const int mhe = mhe_p[0];

  const bool maskAddr = (cs >= 0) && (s < fce) && (tk < 256);
  int c1 = -1, c2 = -1, c3 = -1;
  if (maskAddr) {
    int sp = s - cs - 1;
    if (sp < 0) sp = 0;
    int q = sp / 5;
    int r = sp - q * 5;
    int addr = q * 8 + r;
    c1 = ADDR_KEY + (addr & 15);
    c2 = ADDR_KEY + 16 + ((addr >> 4) & 15);
    c3 = ADDR_KEY + 32 + ((addr >> 8) & 15);
  }
  const bool memM = (tk == MEM_TOK) && (s < mhe);

  float4 v = reinterpret_cast<const float4*>(table + tk * D)[lane];
  float* vp = reinterpret_cast<float*>(&v);
  const int c0 = lane * 4;
  #pragma unroll
  for (int j = 0; j < 4; ++j) {
    int ch = c0 + j;
    bool hit = (maskAddr && (ch == c1 || ch == c2 || ch == c3)) ||
               (memM && ch == MEM_STORE);
    if (hit) vp[j] = 1.0f;
  }
  reinterpret_cast<float4*>(out + (size_t)t * D)[lane] = v;
}

extern "C" void kernel_launch(void* const* d_in, const int* in_sizes, int n_in,
                              void* d_out, int out_size, void* d_ws, size_t ws_size,
                              hipStream_t stream) {
  const int* tok = (const int*)d_in[0];
  const float* table = (const float*)d_in[1];
  const int* mhe = (const int*)d_in[2];
  float* out = (float*)d_out;

  int* cs = (int*)d_ws;             // B*S ints = 1 MiB
  int* fce = cs + B * S;            // B ints

  nvm_scan_kernel<<<B, 256, 0, stream>>>(tok, cs, fce);
  const int n_tok = B * S;          // 262144
  nvm_main_kernel<<<n_tok / 2, 256, 0, stream>>>(tok, table, cs, fce, mhe, out);
}

// Round 3
// 100.102 us; speedup vs baseline: 1.5204x; 1.5204x over previous
//
#include <hip/hip_runtime.h>
#include <hip/hip_bf16.h>

#define B 32
#define S 8192
#define D 512
#define CODE_START 256
#define CODE_END 257
#define MEM_TOK 258
#define ADDR_KEY 206
#define MEM_STORE 455
#define CHUNK 512
#define NCH (S / CHUNK)  // 16 chunks per row

typedef float f32x4 __attribute__((ext_vector_type(4)));

// ---------------------------------------------------------------------------
// Kernel A: per-chunk local scan. Grid (NCH, B), 256 threads, 2 tokens/thread.
// ---------------------------------------------------------------------------
__global__ __launch_bounds__(256) void nvm_chunk_scan(
    const int* __restrict__ tok, int* __restrict__ cs_local,
    int* __restrict__ carry, int* __restrict__ mince) {
  const int c = blockIdx.x;
  const int b = blockIdx.y;
  const int tid = threadIdx.x;
  const int lane = tid & 63;
  const int wid = tid >> 6;
  const int base = c * CHUNK;
  const int* row = tok + b * S;

  const int s0 = base + 2 * tid, s1 = s0 + 1;
  const int t0 = row[s0], t1 = row[s1];
  int v0 = (t0 == CODE_START) ? s0 : -1;
  int v1 = (t1 == CODE_START) ? s1 : -1;
  const int i1 = max(v0, v1);  // pair-inclusive

  // wave-64 inclusive max scan over pair totals
  int incl = i1;
  #pragma unroll
  for (int off = 1; off < 64; off <<= 1) {
    int u = __shfl_up(incl, off, 64);
    if (lane >= off) incl = max(incl, u);
  }
  int ex = __shfl_up(incl, 1, 64);
  if (lane == 0) ex = -1;

  // min CODE_END reduce
  int m = min((t0 == CODE_END) ? s0 : S, (t1 == CODE_END) ? s1 : S);
  #pragma unroll
  for (int off = 32; off; off >>= 1) m = min(m, __shfl_down(m, off, 64));

  __shared__ int wt[4], wm[4];
  if (lane == 63) wt[wid] = incl;
  if (lane == 0) wm[wid] = m;
  __syncthreads();

  int pre = -1;
  for (int w = 0; w < wid; ++w) pre = max(pre, wt[w]);
  ex = max(ex, pre);
  cs_local[b * S + s0] = max(ex, v0);
  cs_local[b * S + s1] = max(ex, i1);

  if (tid == 0) {
    carry[b * NCH + c] = max(max(wt[0], wt[1]), max(wt[2], wt[3]));
    mince[b * NCH + c] = min(min(wm[0], wm[1]), min(wm[2], wm[3]));
  }
}

// ---------------------------------------------------------------------------
// Kernel B: per-row exclusive prefix-max over chunk carries + fce reduce.
// ---------------------------------------------------------------------------
__global__ __launch_bounds__(64) void nvm_row_prefix(
    const int* __restrict__ carry, const int* __restrict__ mince,
    int* __restrict__ pre, int* __restrict__ fce) {
  const int b = threadIdx.x;
  if (b < B) {
    int run = -1, mn = S;
    for (int c = 0; c < NCH; ++c) {
      pre[b * NCH + c] = run;
      run = max(run, carry[b * NCH + c]);
      mn = min(mn, mince[b * NCH + c]);
    }
    fce[b] = mn;
  }
}

// ---------------------------------------------------------------------------
// Kernel M: gather + patch + nontemporal stream out.
// 128 threads per token (one float4 each), 2 tokens per block-iteration,
// grid-stride over token pairs.
// ---------------------------------------------------------------------------
__global__ __launch_bounds__(256) void nvm_main(
    const int* __restrict__ tok, const float* __restrict__ table,
    const int* __restrict__ cs_local, const int* __restrict__ pre,
    const int* __restrict__ fce, const int* __restrict__ mhe_p,
    float* __restrict__ out) {
  const int lane = threadIdx.x & 127;
  const int half = threadIdx.x >> 7;
  const int mhe = mhe_p[0];
  const int NTP = B * S / 2;
  const int c0 = lane * 4;

  for (int tp = blockIdx.x; tp < NTP; tp += gridDim.x) {
    const int t = tp * 2 + half;
    const int b = t >> 13;
    const int s = t & (S - 1);

    const int tk = tok[t];
    const int cs = max(cs_local[t], pre[b * NCH + (s >> 9)]);
    const int f = fce[b];

    const bool maskAddr = (cs >= 0) && (s < f) && (tk < 256);
    int c1 = -1, c2 = -1, c3 = -1;
    if (maskAddr) {
      int sp = s - cs - 1;
      if (sp < 0) sp = 0;
      int q = sp / 5;
      int r = sp - q * 5;
      int addr = q * 8 + r;
      c1 = ADDR_KEY + (addr & 15);
      c2 = ADDR_KEY + 16 + ((addr >> 4) & 15);
      c3 = ADDR_KEY + 32 + ((addr >> 8) & 15);
    }
    const bool memM = (tk == MEM_TOK) && (s < mhe);

    f32x4 v = *reinterpret_cast<const f32x4*>(table + tk * D + c0);
    #pragma unroll
    for (int j = 0; j < 4; ++j) {
      int ch = c0 + j;
      bool hit = (maskAddr && (ch == c1 || ch == c2 || ch == c3)) ||
                 (memM && ch == MEM_STORE);
      if (hit) v[j] = 1.0f;
    }
    f32x4* dst = reinterpret_cast<f32x4*>(out + (size_t)t * D + c0);
    __builtin_nontemporal_store(v, dst);
  }
}

extern "C" void kernel_launch(void* const* d_in, const int* in_sizes, int n_in,
                              void* d_out, int out_size, void* d_ws, size_t ws_size,
                              hipStream_t stream) {
  const int* tok = (const int*)d_in[0];
  const float* table = (const float*)d_in[1];
  const int* mhe = (const int*)d_in[2];
  float* out = (float*)d_out;

  int* cs_local = (int*)d_ws;                 // B*S ints = 1 MiB
  int* carry = cs_local + B * S;              // B*NCH
  int* mince = carry + B * NCH;               // B*NCH
  int* pre = mince + B * NCH;                 // B*NCH
  int* fce = pre + B * NCH;                   // B

  nvm_chunk_scan<<<dim3(NCH, B), 256, 0, stream>>>(tok, cs_local, carry, mince);
  nvm_row_prefix<<<1, 64, 0, stream>>>(carry, mince, pre, fce);
  nvm_main<<<4096, 256, 0, stream>>>(tok, table, cs_local, pre, fce, mhe, out);
}